// Round 10
// baseline (223.624 us; speedup 1.0000x reference)
//
#include <hip/hip_runtime.h>
#include <hip/hip_bf16.h>
#include <math.h>

// B=2, S=2048, D=2048, H=16, KV=4, HD=128, n_rep=4
// qkv layout per row (b*2048+s): [0,2048) q | [2048,2560) k  (v goes straight to vt)
// wqkv is column-PERMUTED for q/k heads: head-local col c holds orig d = (c>>1)+((c&1)<<6)
// Q is scaled by (1/sqrt(128))*log2(e): flash softmax runs in exp2 domain.

typedef __attribute__((ext_vector_type(4))) float f32x4;
typedef __attribute__((ext_vector_type(16))) float f32x16;
typedef __attribute__((ext_vector_type(8))) short short8;
typedef __attribute__((ext_vector_type(4))) unsigned u32x4;
typedef __attribute__((ext_vector_type(4))) unsigned short u16x4;
typedef __attribute__((ext_vector_type(8))) unsigned short u16x8;

static __device__ __forceinline__ unsigned short f2bf(float x) {
    unsigned u = __builtin_bit_cast(unsigned, x);
    u += 0x7fffu + ((u >> 16) & 1u);          // RNE
    return (unsigned short)(u >> 16);
}
static __device__ __forceinline__ float exp2_fast(float x) {
    float r;
    asm volatile("v_exp_f32 %0, %1" : "=v"(r) : "v"(x));
    return r;
}
static __device__ __forceinline__ unsigned cvt_pk_bf16(float a, float b) {
    unsigned r;                                // low16 = bf16(a), high16 = bf16(b)
    asm("v_cvt_pk_bf16_f32 %0, %1, %2" : "=v"(r) : "v"(a), "v"(b));
    return r;
}
static __device__ __forceinline__ short8 pack4(unsigned a, unsigned b, unsigned c, unsigned d) {
    u32x4 v; v.x = a; v.y = b; v.z = c; v.w = d;
    return __builtin_bit_cast(short8, v);
}
static __device__ __forceinline__ void gload16(const unsigned short* g, unsigned short* lds) {
    __builtin_amdgcn_global_load_lds((const __attribute__((address_space(1))) void*)g,
                                     (__attribute__((address_space(3))) void*)lds, 16, 0, 0);
}

// ---------------- fused prep: hs->bf16 | wqkv permuted concat | wo->bf16 | rope table ----
__global__ __launch_bounds__(256) void k_prep(const float* __restrict__ hs,
                                              const float* __restrict__ wq,
                                              const float* __restrict__ wk,
                                              const float* __restrict__ wv,
                                              const float* __restrict__ wo,
                                              const int* __restrict__ pos_ids,
                                              unsigned short* __restrict__ hsb,
                                              unsigned short* __restrict__ wqkvb,
                                              unsigned short* __restrict__ wob,
                                              float2* __restrict__ tb) {
    long idx = (long)blockIdx.x * 256 + threadIdx.x;
    if (idx < 2097152) {                       // hs -> bf16
        f32x4 v = ((const f32x4*)hs)[idx];
        u16x4 o;
        o.x = f2bf(v.x); o.y = f2bf(v.y); o.z = f2bf(v.z); o.w = f2bf(v.w);
        ((u16x4*)hsb)[idx] = o;
    } else if (idx < 3670016) {                // wqkv concat (q/k col-permuted)
        long i = idx - 2097152;
        long flat = i * 4;
        int row = (int)(flat >> 11);
        int col = (int)(flat & 2047);
        const float* src;
        if (row < 2560) {
            int base = row & 2047;
            int hh = base >> 7, ii = base & 127;
            int d = (ii >> 1) + ((ii & 1) << 6);
            src = (row < 2048 ? wq : wk) + (size_t)(hh * 128 + d) * 2048;
        } else {
            src = wv + (size_t)(row - 2560) * 2048;
        }
        f32x4 v = *(const f32x4*)(src + col);
        u16x4 o;
        o.x = f2bf(v.x); o.y = f2bf(v.y); o.z = f2bf(v.z); o.w = f2bf(v.w);
        *(u16x4*)(wqkvb + flat) = o;
    } else if (idx < 4718592) {                // wo -> bf16
        long i = idx - 3670016;
        f32x4 v = ((const f32x4*)wo)[i];
        u16x4 o;
        o.x = f2bf(v.x); o.y = f2bf(v.y); o.z = f2bf(v.z); o.w = f2bf(v.w);
        ((u16x4*)wob)[i] = o;
    } else {                                   // rope table (f32 fast path)
        long j = idx - 4718592;                // [0, 262144)
        int r = (int)(j >> 6);
        int i = (int)(j & 63);
        float pos = (float)pos_ids[r];
        float invf = exp2f((float)i * -0.20762050593046f);  // 10000^(-i/64)
        float arg  = pos * invf;
        float s, c;
        sincosf(arg, &s, &c);                  // accurate f32 sincos
        tb[(size_t)r * 64 + i] = make_float2(c, s);
    }
}

// ---------------- GEMM (R6 known-good): C[M][N] = A[M][K] * W[N][K]^T ----------------
// 128x128 tile, BK=32, 4 waves (2x2), dbuf LDS + global_load_lds w16 + counted vmcnt.
// XCD-aware bijective block swizzle.
// EPI 0: f32 store (O-proj). EPI 1: fused QKV epilogue (RoPE q/k, V transposed to vt).
template <int EPI>
__global__ __launch_bounds__(256) void k_gemm(const unsigned short* __restrict__ A,
                                              const unsigned short* __restrict__ W,
                                              float* __restrict__ Cf,
                                              unsigned short* __restrict__ qkvt,
                                              unsigned short* __restrict__ vtb,
                                              const float2* __restrict__ tb,
                                              int M, int N, int K) {
    __shared__ unsigned short As[2][4096];   // 128 rows x 32 shorts
    __shared__ unsigned short Ws[2][4096];
    const int tid = threadIdx.x;
    const int lane = tid & 63;
    const int w = tid >> 6;
    const int q = lane & 15, g = lane >> 4;
    const int wr = w >> 1, wc = w & 1;

    // XCD swizzle (bijective: gridDim.x*gridDim.y % 8 == 0)
    const int nwg = gridDim.x * gridDim.y;
    const int id = blockIdx.y * gridDim.x + blockIdx.x;
    const int swz_id = (id & 7) * (nwg >> 3) + (id >> 3);
    const int bx = swz_id % gridDim.x;
    const int by = swz_id / gridDim.x;
    const long mbase = (long)by * 128;
    const long nbase = (long)bx * 128;

    const unsigned short* gA[2];
    const unsigned short* gW[2];
    #pragma unroll
    for (int j = 0; j < 2; ++j) {
        int r = j * 64 + (tid >> 2);
        int slot = (tid & 3) ^ ((r >> 1) & 3);
        gA[j] = A + (size_t)(mbase + r) * K + slot * 8;
        gW[j] = W + (size_t)(nbase + r) * K + slot * 8;
    }
    const int sa = (g ^ ((q >> 1) & 3)) * 8;   // read slot offset (shorts)

    f32x4 acc[4][4];
    #pragma unroll
    for (int m = 0; m < 4; ++m)
        #pragma unroll
        for (int n = 0; n < 4; ++n) acc[m][n] = (f32x4){0.f, 0.f, 0.f, 0.f};

    auto STAGE = [&](int buf) {
        #pragma unroll
        for (int j = 0; j < 2; ++j) {
            gload16(gA[j], &As[buf][j * 2048 + w * 512]);
            gload16(gW[j], &Ws[buf][j * 2048 + w * 512]);
            gA[j] += 32; gW[j] += 32;
        }
    };

    const int nk = K >> 5;
    STAGE(0);
    int cur = 0;
    for (int t = 0; t < nk; ++t) {
        if (t) __builtin_amdgcn_s_barrier();            // prev buffer free
        if (t + 1 < nk) {
            STAGE(cur ^ 1);
            asm volatile("s_waitcnt vmcnt(4)" ::: "memory");   // this tile's loads done
        } else {
            asm volatile("s_waitcnt vmcnt(0)" ::: "memory");
        }
        __builtin_amdgcn_s_barrier();                   // tile visible to all waves

        short8 af[4], bfr[4];
        #pragma unroll
        for (int m = 0; m < 4; ++m) af[m] = *(const short8*)&As[cur][(wr * 64 + m * 16 + q) * 32 + sa];
        #pragma unroll
        for (int n = 0; n < 4; ++n) bfr[n] = *(const short8*)&Ws[cur][(wc * 64 + n * 16 + q) * 32 + sa];
        #pragma unroll
        for (int m = 0; m < 4; ++m)
            #pragma unroll
            for (int n = 0; n < 4; ++n)
                acc[m][n] = __builtin_amdgcn_mfma_f32_16x16x32_bf16(af[m], bfr[n], acc[m][n], 0, 0, 0);
        cur ^= 1;
    }

    if (EPI == 0) {
        #pragma unroll
        for (int m = 0; m < 4; ++m)
            #pragma unroll
            for (int n = 0; n < 4; ++n)
                #pragma unroll
                for (int rr = 0; rr < 4; ++rr) {
                    long row = mbase + wr * 64 + m * 16 + 4 * g + rr;
                    long col = nbase + wc * 64 + n * 16 + q;
                    Cf[row * N + col] = acc[m][n][rr];
                }
    } else {
        const int tile = bx;
        if (tile >= 20) {
            // V tile -> vt[(b*4+kv)*128+c][s], 4 consecutive s per store
            const int kv = tile - 20;
            #pragma unroll
            for (int m = 0; m < 4; ++m)
                #pragma unroll
                for (int n = 0; n < 4; ++n) {
                    int c = wc * 64 + n * 16 + q;
                    long r0 = mbase + wr * 64 + m * 16 + 4 * g;
                    int b = (int)(r0 >> 11), s0 = (int)(r0 & 2047);
                    uint2 pk;
                    pk.x = cvt_pk_bf16(acc[m][n][0], acc[m][n][1]);
                    pk.y = cvt_pk_bf16(acc[m][n][2], acc[m][n][3]);
                    *(uint2*)(vtb + (size_t)((b * 4 + kv) * 128 + c) * 2048 + s0) = pk;
                }
        } else {
            // q/k tile: RoPE from permuted cols; un-permute on store
            const float scale = (tile < 16) ? 0.12751744f : 1.0f;  // (1/sqrt(128))*log2e for q
            const float sgn = (q & 1) ? 1.f : -1.f;
            #pragma unroll
            for (int m = 0; m < 4; ++m)
                #pragma unroll
                for (int rr = 0; rr < 4; ++rr) {
                    long row = mbase + wr * 64 + m * 16 + 4 * g + rr;
                    #pragma unroll
                    for (int n = 0; n < 4; ++n) {
                        int c = wc * 64 + n * 16 + q;
                        float x = acc[m][n][rr];
                        float p = __shfl_xor(x, 1);
                        float2 cs = tb[row * 64 + (c >> 1)];
                        float y = (x * cs.x + sgn * (p * cs.y)) * scale;
                        int dorig = (c >> 1) + ((c & 1) << 6);
                        long col = (tile < 16) ? (tile * 128 + dorig)
                                               : (2048 + (tile - 16) * 128 + dorig);
                        qkvt[row * 3072 + col] = f2bf(y);
                    }
                }
        }
    }
}

// ---------------- Flash attention v10: 32x32 MFMA, in-register softmax/P ----------------
// 512 blocks (one (b,kvh) per XCD), 4 waves x 32 queries, KVBLK=64, exp2-domain softmax.
// Swapped QK^T with mfma_32x32x16: query = lane&31 -> softmax fully lane-local
// (one shfl_xor(32) per reduce). P stays in registers: cvt_pk + pre-selected
// shfl_xor(32) builds PV B-operands directly (no LDS P-bounce).
__global__ __launch_bounds__(256, 2) void k_flash(const unsigned short* __restrict__ qkv,
                                                  const unsigned short* __restrict__ vt,
                                                  unsigned short* __restrict__ aout) {
    __shared__ unsigned short Ks[2][8192];   // 64 keys x 128 hd, dbuf (slot-swizzled)
    __shared__ unsigned short Vs[2][8192];   // 128 d x 64 keys, dbuf (slot-swizzled)
    const int wg = blockIdx.x;
    const int kvg = wg & 7;            // b*4+kvh -> pinned per XCD
    const int inner = wg >> 3;         // 0..63
    const int h_in = inner & 3;
    const int qt = inner >> 2;         // 0..15
    const int b = kvg >> 2, kvh = kvg & 3;
    const int h = kvh * 4 + h_in;
    const int tid = threadIdx.x;
    const int w = tid >> 6, lane = tid & 63;
    const int ql = lane & 31;          // this lane's query (col of 32x32 D)
    const int hi = lane >> 5;          // k-group half
    const int q7 = ql & 7;
    const int qrow = qt * 128 + w * 32;

    // Q fragments (B-operand): qf[s] = Q[qrow+ql][s*16 + hi*8 .. +7], s=0..7
    short8 qf[8];
    {
        const unsigned short* Qp = qkv + (size_t)(b * 2048 + qrow + ql) * 3072 + h * 128 + hi * 8;
        #pragma unroll
        for (int s = 0; s < 8; ++s) qf[s] = *(const short8*)(Qp + s * 16);
    }

    const unsigned short* Kbase = qkv + (size_t)(b * 2048) * 3072 + 2048 + kvh * 128;
    const unsigned short* Vbase = vt + (size_t)((b * 4 + kvh) * 128) * 2048;
    const unsigned short* gK[4];
    const unsigned short* gV[4];
    #pragma unroll
    for (int i = 0; i < 4; ++i) {
        int rowK = w * 16 + i * 4 + (lane >> 4);
        gK[i] = Kbase + (size_t)rowK * 3072 + (((lane & 15) ^ (rowK & 7)) << 3);
        int rowV = w * 32 + i * 8 + (lane >> 3);
        gV[i] = Vbase + (size_t)rowV * 2048 + (((lane & 7) ^ (rowV & 7)) << 3);
    }

    float m_run = -INFINITY, l_run = 0.f;
    f32x16 o[4];
    #pragma unroll
    for (int dt = 0; dt < 4; ++dt)
        #pragma unroll
        for (int j = 0; j < 16; ++j) o[dt][j] = 0.f;

    auto STAGE = [&](int buf) {
        #pragma unroll
        for (int i = 0; i < 4; ++i) {
            gload16(gK[i], &Ks[buf][w * 2048 + i * 512]);
            gload16(gV[i], &Vs[buf][w * 2048 + i * 512]);
            gK[i] += 64 * 3072;
            gV[i] += 64;
        }
    };

    STAGE(0);
    int cur = 0;
    for (int t0 = 0; t0 < 32; ++t0) {
        if (t0 > 0) __builtin_amdgcn_s_barrier();
        if (t0 + 1 < 32) {
            STAGE(cur ^ 1);
            asm volatile("s_waitcnt vmcnt(8)" ::: "memory");
        } else {
            asm volatile("s_waitcnt vmcnt(0)" ::: "memory");
        }
        __builtin_amdgcn_s_barrier();

        const unsigned short* Kt = Ks[cur];
        const unsigned short* Vt = Vs[cur];

        // ---- QK^T: st[tile] = S^T[key = tile*32 + crow][query ql], 8 hd-slices each ----
        f32x16 st0, st1;
        #pragma unroll
        for (int j = 0; j < 16; ++j) { st0[j] = 0.f; st1[j] = 0.f; }
        #pragma unroll
        for (int s = 0; s < 8; ++s) {
            int slot = ((2 * s + hi) ^ q7) * 8;
            short8 kf0 = *(const short8*)&Kt[(ql) * 128 + slot];
            short8 kf1 = *(const short8*)&Kt[(32 + ql) * 128 + slot];
            st0 = __builtin_amdgcn_mfma_f32_32x32x16_bf16(kf0, qf[s], st0, 0, 0, 0);
            st1 = __builtin_amdgcn_mfma_f32_32x32x16_bf16(kf1, qf[s], st1, 0, 0, 0);
        }

        // ---- softmax (lane-local, exp2 domain, defer-max) ----
        float mx = -INFINITY;
        #pragma unroll
        for (int j = 0; j < 16; ++j) mx = fmaxf(mx, fmaxf(st0[j], st1[j]));
        mx = fmaxf(mx, __shfl_xor(mx, 32));
        if (__any(mx - m_run > 8.0f)) {
            float mn = fmaxf(m_run, mx);
            float sc = exp2_fast(m_run - mn);
            l_run *= sc;
            #pragma unroll
            for (int dt = 0; dt < 4; ++dt)
                #pragma unroll
                for (int j = 0; j < 16; ++j) o[dt][j] *= sc;
            m_run = mn;
        }
        float ls = 0.f;
        #pragma unroll
        for (int j = 0; j < 16; ++j) {
            st0[j] = exp2_fast(st0[j] - m_run);
            st1[j] = exp2_fast(st1[j] - m_run);
            ls += st0[j] + st1[j];
        }
        ls += __shfl_xor(ls, 32);
        l_run += ls;

        // ---- P -> bf16 PV B-operands, fully in-register ----
        // W[m] = pk(p[2m],p[2m+1]); one pre-selected shfl serves both halves (m214 trick)
        short8 PB[4];
        #pragma unroll
        for (int tile = 0; tile < 2; ++tile) {
            const f32x16& pe = tile ? st1 : st0;
            unsigned W0 = cvt_pk_bf16(pe[0], pe[1]),   W1 = cvt_pk_bf16(pe[2], pe[3]);
            unsigned W2 = cvt_pk_bf16(pe[4], pe[5]),   W3 = cvt_pk_bf16(pe[6], pe[7]);
            unsigned W4 = cvt_pk_bf16(pe[8], pe[9]),   W5 = cvt_pk_bf16(pe[10], pe[11]);
            unsigned W6 = cvt_pk_bf16(pe[12], pe[13]), W7 = cvt_pk_bf16(pe[14], pe[15]);
            unsigned S1 = (unsigned)__shfl_xor((int)(hi ? W0 : W2), 32);
            unsigned S2 = (unsigned)__shfl_xor((int)(hi ? W1 : W3), 32);
            unsigned S3 = (unsigned)__shfl_xor((int)(hi ? W4 : W6), 32);
            unsigned S4 = (unsigned)__shfl_xor((int)(hi ? W5 : W7), 32);
            PB[tile * 2 + 0] = hi ? pack4(S1, S2, W2, W3) : pack4(W0, W1, S1, S2);
            PB[tile * 2 + 1] = hi ? pack4(S3, S4, W6, W7) : pack4(W4, W5, S3, S4);
        }

        // ---- PV: O^T[d][q] += V^T[d][k] * P^T[k][q] ----
        #pragma unroll
        for (int dt = 0; dt < 4; ++dt) {
            int vrb = (dt * 32 + ql) * 64;
            f32x16 a = o[dt];
            #pragma unroll
            for (int ks = 0; ks < 4; ++ks) {
                int slot = ((2 * ks + hi) ^ q7) * 8;
                short8 vf = *(const short8*)&Vt[vrb + slot];
                a = __builtin_amdgcn_mfma_f32_32x32x16_bf16(vf, PB[ks], a, 0, 0, 0);
            }
            o[dt] = a;
        }
        cur ^= 1;
    }

    // ---- normalize (lane-local l) and store: row = b*2048+qrow+ql, d = dt*32+rq*8+hi*4 ----
    float li = 1.0f / l_run;
    unsigned short* op = aout + (size_t)(b * 2048 + qrow + ql) * 2048 + h * 128;
    #pragma unroll
    for (int dt = 0; dt < 4; ++dt)
        #pragma unroll
        for (int rq = 0; rq < 4; ++rq) {
            uint2 pk;
            pk.x = cvt_pk_bf16(o[dt][rq * 4 + 0] * li, o[dt][rq * 4 + 1] * li);
            pk.y = cvt_pk_bf16(o[dt][rq * 4 + 2] * li, o[dt][rq * 4 + 3] * li);
            *(uint2*)(op + dt * 32 + rq * 8 + hi * 4) = pk;
        }
}

extern "C" void kernel_launch(void* const* d_in, const int* in_sizes, int n_in,
                              void* d_out, int out_size, void* d_ws, size_t ws_size,
                              hipStream_t stream) {
    (void)in_sizes; (void)n_in; (void)out_size; (void)ws_size;
    const float* hs = (const float*)d_in[0];
    const int* pos  = (const int*)d_in[1];
    const float* wq = (const float*)d_in[2];
    const float* wk = (const float*)d_in[3];
    const float* wv = (const float*)d_in[4];
    const float* wo = (const float*)d_in[5];
    float* out = (float*)d_out;

    unsigned short* hsb   = (unsigned short*)d_ws;              // 4096*2048
    unsigned short* wqkvb = hsb + (size_t)4096 * 2048;          // 3072*2048
    unsigned short* wob   = wqkvb + (size_t)3072 * 2048;        // 2048*2048
    unsigned short* qkvt  = wob + (size_t)2048 * 2048;          // 4096*3072 (q|k used)
    unsigned short* vtb   = qkvt + (size_t)4096 * 3072;         // 8*128*2048
    float2* tb            = (float2*)(vtb + (size_t)8 * 128 * 2048);   // 4096*64
    unsigned short* aoutb = (unsigned short*)(tb + (size_t)4096 * 64); // 4096*2048

    k_prep<<<19456, 256, 0, stream>>>(hs, wq, wk, wv, wo, pos, hsb, wqkvb, wob, tb);
    k_gemm<1><<<dim3(24, 32), 256, 0, stream>>>(hsb, wqkvb, nullptr, qkvt, vtb, tb, 4096, 3072, 2048);
    k_flash<<<dim3(512), 256, 0, stream>>>(qkvt, vtb, aoutb);
    k_gemm<0><<<dim3(16, 32), 256, 0, stream>>>(aoutb, wob, out, nullptr, nullptr, nullptr, 4096, 2048, 2048);
}

// Round 11
// 220.541 us; speedup vs baseline: 1.0140x; 1.0140x over previous
//
#include <hip/hip_runtime.h>
#include <hip/hip_bf16.h>
#include <math.h>

// B=2, S=2048, D=2048, H=16, KV=4, HD=128, n_rep=4
// qkv layout per row (b*2048+s): [0,2048) q | [2048,2560) k  (v goes straight to vt)
// wqkv is column-PERMUTED for q/k heads: head-local col c holds orig d = (c>>1)+((c&1)<<6)
// Q is scaled by (1/sqrt(128))*log2(e): flash softmax runs in exp2 domain.

typedef __attribute__((ext_vector_type(4))) float f32x4;
typedef __attribute__((ext_vector_type(8))) short short8;
typedef __attribute__((ext_vector_type(4))) unsigned short u16x4;
typedef __attribute__((ext_vector_type(8))) unsigned short u16x8;

static __device__ __forceinline__ unsigned short f2bf(float x) {
    unsigned u = __builtin_bit_cast(unsigned, x);
    u += 0x7fffu + ((u >> 16) & 1u);          // RNE
    return (unsigned short)(u >> 16);
}
static __device__ __forceinline__ float exp2_fast(float x) {
    float r;
    asm volatile("v_exp_f32 %0, %1" : "=v"(r) : "v"(x));
    return r;
}
static __device__ __forceinline__ unsigned cvt_pk_bf16(float a, float b) {
    unsigned r;                                // low16 = bf16(a), high16 = bf16(b)
    asm("v_cvt_pk_bf16_f32 %0, %1, %2" : "=v"(r) : "v"(a), "v"(b));
    return r;
}
static __device__ __forceinline__ void gload16(const unsigned short* g, unsigned short* lds) {
    __builtin_amdgcn_global_load_lds((const __attribute__((address_space(1))) void*)g,
                                     (__attribute__((address_space(3))) void*)lds, 16, 0, 0);
}

// ---------------- fused prep: hs->bf16 | wqkv permuted concat | wo->bf16 | rope table ----
__global__ __launch_bounds__(256) void k_prep(const float* __restrict__ hs,
                                              const float* __restrict__ wq,
                                              const float* __restrict__ wk,
                                              const float* __restrict__ wv,
                                              const float* __restrict__ wo,
                                              const int* __restrict__ pos_ids,
                                              unsigned short* __restrict__ hsb,
                                              unsigned short* __restrict__ wqkvb,
                                              unsigned short* __restrict__ wob,
                                              float2* __restrict__ tb) {
    long idx = (long)blockIdx.x * 256 + threadIdx.x;
    if (idx < 2097152) {                       // hs -> bf16
        f32x4 v = ((const f32x4*)hs)[idx];
        u16x4 o;
        o.x = f2bf(v.x); o.y = f2bf(v.y); o.z = f2bf(v.z); o.w = f2bf(v.w);
        ((u16x4*)hsb)[idx] = o;
    } else if (idx < 3670016) {                // wqkv concat (q/k col-permuted)
        long i = idx - 2097152;
        long flat = i * 4;
        int row = (int)(flat >> 11);
        int col = (int)(flat & 2047);
        const float* src;
        if (row < 2560) {
            int base = row & 2047;
            int hh = base >> 7, ii = base & 127;
            int d = (ii >> 1) + ((ii & 1) << 6);
            src = (row < 2048 ? wq : wk) + (size_t)(hh * 128 + d) * 2048;
        } else {
            src = wv + (size_t)(row - 2560) * 2048;
        }
        f32x4 v = *(const f32x4*)(src + col);
        u16x4 o;
        o.x = f2bf(v.x); o.y = f2bf(v.y); o.z = f2bf(v.z); o.w = f2bf(v.w);
        *(u16x4*)(wqkvb + flat) = o;
    } else if (idx < 4718592) {                // wo -> bf16
        long i = idx - 3670016;
        f32x4 v = ((const f32x4*)wo)[i];
        u16x4 o;
        o.x = f2bf(v.x); o.y = f2bf(v.y); o.z = f2bf(v.z); o.w = f2bf(v.w);
        ((u16x4*)wob)[i] = o;
    } else {                                   // rope table (f32 fast path)
        long j = idx - 4718592;                // [0, 262144)
        int r = (int)(j >> 6);
        int i = (int)(j & 63);
        float pos = (float)pos_ids[r];
        float invf = exp2f((float)i * -0.20762050593046f);  // 10000^(-i/64)
        float arg  = pos * invf;
        float s, c;
        sincosf(arg, &s, &c);                  // accurate f32 sincos
        tb[(size_t)r * 64 + i] = make_float2(c, s);
    }
}

// ---------------- GEMM (R6 known-good): C[M][N] = A[M][K] * W[N][K]^T ----------------
// 128x128 tile, BK=32, 4 waves (2x2), dbuf LDS + global_load_lds w16 + counted vmcnt.
// XCD-aware bijective block swizzle.
// EPI 0: f32 store (O-proj). EPI 1: fused QKV epilogue (RoPE q/k, V transposed to vt).
template <int EPI>
__global__ __launch_bounds__(256) void k_gemm(const unsigned short* __restrict__ A,
                                              const unsigned short* __restrict__ W,
                                              float* __restrict__ Cf,
                                              unsigned short* __restrict__ qkvt,
                                              unsigned short* __restrict__ vtb,
                                              const float2* __restrict__ tb,
                                              int M, int N, int K) {
    __shared__ unsigned short As[2][4096];   // 128 rows x 32 shorts
    __shared__ unsigned short Ws[2][4096];
    const int tid = threadIdx.x;
    const int lane = tid & 63;
    const int w = tid >> 6;
    const int q = lane & 15, g = lane >> 4;
    const int wr = w >> 1, wc = w & 1;

    // XCD swizzle (bijective: gridDim.x*gridDim.y % 8 == 0)
    const int nwg = gridDim.x * gridDim.y;
    const int id = blockIdx.y * gridDim.x + blockIdx.x;
    const int swz_id = (id & 7) * (nwg >> 3) + (id >> 3);
    const int bx = swz_id % gridDim.x;
    const int by = swz_id / gridDim.x;
    const long mbase = (long)by * 128;
    const long nbase = (long)bx * 128;

    const unsigned short* gA[2];
    const unsigned short* gW[2];
    #pragma unroll
    for (int j = 0; j < 2; ++j) {
        int r = j * 64 + (tid >> 2);
        int slot = (tid & 3) ^ ((r >> 1) & 3);
        gA[j] = A + (size_t)(mbase + r) * K + slot * 8;
        gW[j] = W + (size_t)(nbase + r) * K + slot * 8;
    }
    const int sa = (g ^ ((q >> 1) & 3)) * 8;   // read slot offset (shorts)

    f32x4 acc[4][4];
    #pragma unroll
    for (int m = 0; m < 4; ++m)
        #pragma unroll
        for (int n = 0; n < 4; ++n) acc[m][n] = (f32x4){0.f, 0.f, 0.f, 0.f};

    auto STAGE = [&](int buf) {
        #pragma unroll
        for (int j = 0; j < 2; ++j) {
            gload16(gA[j], &As[buf][j * 2048 + w * 512]);
            gload16(gW[j], &Ws[buf][j * 2048 + w * 512]);
            gA[j] += 32; gW[j] += 32;
        }
    };

    const int nk = K >> 5;
    STAGE(0);
    int cur = 0;
    for (int t = 0; t < nk; ++t) {
        if (t) __builtin_amdgcn_s_barrier();            // prev buffer free
        if (t + 1 < nk) {
            STAGE(cur ^ 1);
            asm volatile("s_waitcnt vmcnt(4)" ::: "memory");   // this tile's loads done
        } else {
            asm volatile("s_waitcnt vmcnt(0)" ::: "memory");
        }
        __builtin_amdgcn_s_barrier();                   // tile visible to all waves

        short8 af[4], bfr[4];
        #pragma unroll
        for (int m = 0; m < 4; ++m) af[m] = *(const short8*)&As[cur][(wr * 64 + m * 16 + q) * 32 + sa];
        #pragma unroll
        for (int n = 0; n < 4; ++n) bfr[n] = *(const short8*)&Ws[cur][(wc * 64 + n * 16 + q) * 32 + sa];
        #pragma unroll
        for (int m = 0; m < 4; ++m)
            #pragma unroll
            for (int n = 0; n < 4; ++n)
                acc[m][n] = __builtin_amdgcn_mfma_f32_16x16x32_bf16(af[m], bfr[n], acc[m][n], 0, 0, 0);
        cur ^= 1;
    }

    if (EPI == 0) {
        #pragma unroll
        for (int m = 0; m < 4; ++m)
            #pragma unroll
            for (int n = 0; n < 4; ++n)
                #pragma unroll
                for (int rr = 0; rr < 4; ++rr) {
                    long row = mbase + wr * 64 + m * 16 + 4 * g + rr;
                    long col = nbase + wc * 64 + n * 16 + q;
                    Cf[row * N + col] = acc[m][n][rr];
                }
    } else {
        const int tile = bx;
        if (tile >= 20) {
            // V tile -> vt[(b*4+kv)*128+c][s], 4 consecutive s per store
            const int kv = tile - 20;
            #pragma unroll
            for (int m = 0; m < 4; ++m)
                #pragma unroll
                for (int n = 0; n < 4; ++n) {
                    int c = wc * 64 + n * 16 + q;
                    long r0 = mbase + wr * 64 + m * 16 + 4 * g;
                    int b = (int)(r0 >> 11), s0 = (int)(r0 & 2047);
                    uint2 pk;
                    pk.x = cvt_pk_bf16(acc[m][n][0], acc[m][n][1]);
                    pk.y = cvt_pk_bf16(acc[m][n][2], acc[m][n][3]);
                    *(uint2*)(vtb + (size_t)((b * 4 + kv) * 128 + c) * 2048 + s0) = pk;
                }
        } else {
            // q/k tile: RoPE from permuted cols; un-permute on store
            const float scale = (tile < 16) ? 0.12751744f : 1.0f;  // (1/sqrt(128))*log2e for q
            const float sgn = (q & 1) ? 1.f : -1.f;
            #pragma unroll
            for (int m = 0; m < 4; ++m)
                #pragma unroll
                for (int rr = 0; rr < 4; ++rr) {
                    long row = mbase + wr * 64 + m * 16 + 4 * g + rr;
                    #pragma unroll
                    for (int n = 0; n < 4; ++n) {
                        int c = wc * 64 + n * 16 + q;
                        float x = acc[m][n][rr];
                        float p = __shfl_xor(x, 1);
                        float2 cs = tb[row * 64 + (c >> 1)];
                        float y = (x * cs.x + sgn * (p * cs.y)) * scale;
                        int dorig = (c >> 1) + ((c & 1) << 6);
                        long col = (tile < 16) ? (tile * 128 + dorig)
                                               : (2048 + (tile - 16) * 128 + dorig);
                        qkvt[row * 3072 + col] = f2bf(y);
                    }
                }
        }
    }
}

// ---------------- Flash attention (R9 known-good + setprio around MFMA clusters) ----
// 512 blocks (one (b,kvh) per XCD), 4 waves x 32 queries, KVBLK=64, exp2-domain softmax.
// K and V LDS-staged (dbuf, gload_lds, XOR-swizzle), counted vmcnt(8).
__global__ __launch_bounds__(256, 2) void k_flash(const unsigned short* __restrict__ qkv,
                                                  const unsigned short* __restrict__ vt,
                                                  unsigned short* __restrict__ aout) {
    __shared__ unsigned short Ks[2][8192];   // 64 keys x 128 hd, dbuf
    __shared__ unsigned short Vs[2][8192];   // 128 d x 64 keys, dbuf
    __shared__ unsigned short Plds[4][1152]; // per-wave 16 x 72
    const int wg = blockIdx.x;
    const int kvg = wg & 7;            // b*4+kvh -> pinned per XCD
    const int inner = wg >> 3;         // 0..63
    const int h_in = inner & 3;
    const int qt = inner >> 2;         // 0..15
    const int b = kvg >> 2, kvh = kvg & 3;
    const int h = kvh * 4 + h_in;
    const int tid = threadIdx.x;
    const int w = tid >> 6, lane = tid & 63;
    const int q = lane & 15, g = lane >> 4;
    const int qrow = qt * 128 + w * 32;

    short8 qf[2][4];
    #pragma unroll
    for (int u = 0; u < 2; ++u) {
        const unsigned short* Qp = qkv + (size_t)(b * 2048 + qrow + u * 16 + q) * 3072 + h * 128 + g * 8;
        #pragma unroll
        for (int t = 0; t < 4; ++t) qf[u][t] = *(const short8*)(Qp + t * 32);
    }

    const unsigned short* Kbase = qkv + (size_t)(b * 2048) * 3072 + 2048 + kvh * 128;
    const unsigned short* Vbase = vt + (size_t)((b * 4 + kvh) * 128) * 2048;
    const unsigned short* gK[4];
    const unsigned short* gV[4];
    #pragma unroll
    for (int i = 0; i < 4; ++i) {
        int rowK = w * 16 + i * 4 + (lane >> 4);
        gK[i] = Kbase + (size_t)rowK * 3072 + (((lane & 15) ^ (rowK & 7)) << 3);
        int rowV = w * 32 + i * 8 + (lane >> 3);
        gV[i] = Vbase + (size_t)rowV * 2048 + (((lane & 7) ^ (rowV & 7)) << 3);
    }

    const int swz = (q & 7) << 3;
    int tcK[4];
    #pragma unroll
    for (int t = 0; t < 4; ++t) tcK[t] = (t * 32 + g * 8) ^ swz;

    unsigned short* Pw = Plds[w];

    float m_run[2] = {-INFINITY, -INFINITY};
    float l_run[2] = {0.f, 0.f};
    f32x4 o[2][8];
    #pragma unroll
    for (int u = 0; u < 2; ++u)
        #pragma unroll
        for (int nf = 0; nf < 8; ++nf) o[u][nf] = (f32x4){0.f, 0.f, 0.f, 0.f};

    auto STAGE = [&](int buf) {
        #pragma unroll
        for (int i = 0; i < 4; ++i) {
            gload16(gK[i], &Ks[buf][w * 2048 + i * 512]);
            gload16(gV[i], &Vs[buf][w * 2048 + i * 512]);
            gK[i] += 64 * 3072;
            gV[i] += 64;
        }
    };

    STAGE(0);
    int cur = 0;
    for (int t0 = 0; t0 < 32; ++t0) {
        if (t0 > 0) __builtin_amdgcn_s_barrier();
        if (t0 + 1 < 32) {
            STAGE(cur ^ 1);
            asm volatile("s_waitcnt vmcnt(8)" ::: "memory");
        } else {
            asm volatile("s_waitcnt vmcnt(0)" ::: "memory");
        }
        __builtin_amdgcn_s_barrier();

        const unsigned short* Kt = Ks[cur];
        const unsigned short* Vt = Vs[cur];

        f32x4 st[2][4];
        __builtin_amdgcn_s_setprio(1);
        #pragma unroll
        for (int ks = 0; ks < 4; ++ks) {
            f32x4 a0 = (f32x4){0.f, 0.f, 0.f, 0.f};
            f32x4 a1 = (f32x4){0.f, 0.f, 0.f, 0.f};
            int rb = (ks * 16 + q) * 128;
            #pragma unroll
            for (int t = 0; t < 4; ++t) {
                short8 kf = *(const short8*)&Kt[rb + tcK[t]];
                a0 = __builtin_amdgcn_mfma_f32_16x16x32_bf16(kf, qf[0][t], a0, 0, 0, 0);
                a1 = __builtin_amdgcn_mfma_f32_16x16x32_bf16(kf, qf[1][t], a1, 0, 0, 0);
            }
            st[0][ks] = a0; st[1][ks] = a1;
        }
        __builtin_amdgcn_s_setprio(0);

        short8 vf[8][2];
        #pragma unroll
        for (int nf = 0; nf < 8; ++nf) {
            int rb = (nf * 16 + q) * 64;
            #pragma unroll
            for (int t = 0; t < 2; ++t) vf[nf][t] = *(const short8*)&Vt[rb + tcK[t]];
        }

        #pragma unroll
        for (int u = 0; u < 2; ++u) {
            float mx = fmaxf(
                fmaxf(fmaxf(fmaxf(st[u][0][0], st[u][0][1]), fmaxf(st[u][0][2], st[u][0][3])),
                      fmaxf(fmaxf(st[u][1][0], st[u][1][1]), fmaxf(st[u][1][2], st[u][1][3]))),
                fmaxf(fmaxf(fmaxf(st[u][2][0], st[u][2][1]), fmaxf(st[u][2][2], st[u][2][3])),
                      fmaxf(fmaxf(st[u][3][0], st[u][3][1]), fmaxf(st[u][3][2], st[u][3][3]))));
            mx = fmaxf(mx, __shfl_xor(mx, 16));
            mx = fmaxf(mx, __shfl_xor(mx, 32));
            if (__any(mx - m_run[u] > 8.0f)) {          // defer-max (exp2 domain)
                float mn = fmaxf(m_run[u], mx);
                float sc = exp2_fast(m_run[u] - mn);
                l_run[u] *= sc;
                f32x4 sv;
                #pragma unroll
                for (int rr = 0; rr < 4; ++rr) sv[rr] = __shfl(sc, 4 * g + rr);
                #pragma unroll
                for (int nf = 0; nf < 8; ++nf) o[u][nf] *= sv;
                m_run[u] = mn;
            }
            f32x4 pe[4];
            #pragma unroll
            for (int ks = 0; ks < 4; ++ks)
                #pragma unroll
                for (int rr = 0; rr < 4; ++rr) pe[ks][rr] = exp2_fast(st[u][ks][rr] - m_run[u]);
            f32x4 ls4 = (pe[0] + pe[1]) + (pe[2] + pe[3]);
            float ls = (ls4[0] + ls4[1]) + (ls4[2] + ls4[3]);
            ls += __shfl_xor(ls, 16);
            ls += __shfl_xor(ls, 32);
            l_run[u] += ls;

            #pragma unroll
            for (int ks = 0; ks < 4; ++ks) {
                uint2 pk;
                pk.x = cvt_pk_bf16(pe[ks][0], pe[ks][1]);
                pk.y = cvt_pk_bf16(pe[ks][2], pe[ks][3]);
                *(uint2*)&Pw[q * 72 + ks * 16 + 4 * g] = pk;
            }
            asm volatile("s_waitcnt lgkmcnt(0)" ::: "memory");
            short8 pa0 = *(const short8*)&Pw[q * 72 + g * 8];
            short8 pa1 = *(const short8*)&Pw[q * 72 + 32 + g * 8];

            __builtin_amdgcn_s_setprio(1);
            #pragma unroll
            for (int nf = 0; nf < 8; ++nf) {
                f32x4 a = o[u][nf];
                a = __builtin_amdgcn_mfma_f32_16x16x32_bf16(pa0, vf[nf][0], a, 0, 0, 0);
                a = __builtin_amdgcn_mfma_f32_16x16x32_bf16(pa1, vf[nf][1], a, 0, 0, 0);
                o[u][nf] = a;
            }
            __builtin_amdgcn_s_setprio(0);
        }
        cur ^= 1;
    }

    #pragma unroll
    for (int u = 0; u < 2; ++u) {
        f32x4 li;
        #pragma unroll
        for (int rr = 0; rr < 4; ++rr) li[rr] = __shfl(l_run[u], 4 * g + rr);
        #pragma unroll
        for (int rr = 0; rr < 4; ++rr) li[rr] = 1.0f / li[rr];
        #pragma unroll
        for (int nf = 0; nf < 8; ++nf)
            #pragma unroll
            for (int rr = 0; rr < 4; ++rr) {
                size_t row = (size_t)(b * 2048 + qrow + u * 16 + 4 * g + rr);
                aout[row * 2048 + h * 128 + nf * 16 + q] = f2bf(o[u][nf][rr] * li[rr]);
            }
    }
}

extern "C" void kernel_launch(void* const* d_in, const int* in_sizes, int n_in,
                              void* d_out, int out_size, void* d_ws, size_t ws_size,
                              hipStream_t stream) {
    (void)in_sizes; (void)n_in; (void)out_size; (void)ws_size;
    const float* hs = (const float*)d_in[0];
    const int* pos  = (const int*)d_in[1];
    const float* wq = (const float*)d_in[2];
    const float* wk = (const float*)d_in[3];
    const float* wv = (const float*)d_in[4];
    const float* wo = (const float*)d_in[5];
    float* out = (float*)d_out;

    unsigned short* hsb   = (unsigned short*)d_ws;              // 4096*2048
    unsigned short* wqkvb = hsb + (size_t)4096 * 2048;          // 3072*2048
    unsigned short* wob   = wqkvb + (size_t)3072 * 2048;        // 2048*2048
    unsigned short* qkvt  = wob + (size_t)2048 * 2048;          // 4096*3072 (q|k used)
    unsigned short* vtb   = qkvt + (size_t)4096 * 3072;         // 8*128*2048
    float2* tb            = (float2*)(vtb + (size_t)8 * 128 * 2048);   // 4096*64
    unsigned short* aoutb = (unsigned short*)(tb + (size_t)4096 * 64); // 4096*2048

    k_prep<<<19456, 256, 0, stream>>>(hs, wq, wk, wv, wo, pos, hsb, wqkvb, wob, tb);
    k_gemm<1><<<dim3(24, 32), 256, 0, stream>>>(hsb, wqkvb, nullptr, qkvt, vtb, tb, 4096, 3072, 2048);
    k_flash<<<dim3(512), 256, 0, stream>>>(qkvt, vtb, aoutb);
    k_gemm<0><<<dim3(16, 32), 256, 0, stream>>>(aoutb, wob, out, nullptr, nullptr, nullptr, 4096, 2048, 2048);
}

// Round 13
// 219.307 us; speedup vs baseline: 1.0197x; 1.0056x over previous
//
#include <hip/hip_runtime.h>
#include <hip/hip_bf16.h>
#include <math.h>

// B=2, S=2048, D=2048, H=16, KV=4, HD=128, n_rep=4
// qkv layout per row (b*2048+s): [0,2048) q | [2048,2560) k  (v goes straight to vt)
// wqkv is column-PERMUTED for q/k heads: head-local col c holds orig d = (c>>1)+((c&1)<<6)
// Q is scaled by (1/sqrt(128))*log2(e): flash softmax runs in exp2 domain.

typedef __attribute__((ext_vector_type(4))) float f32x4;
typedef __attribute__((ext_vector_type(8))) short short8;
typedef __attribute__((ext_vector_type(4))) unsigned short u16x4;
typedef __attribute__((ext_vector_type(8))) unsigned short u16x8;

static __device__ __forceinline__ unsigned short f2bf(float x) {
    unsigned u = __builtin_bit_cast(unsigned, x);
    u += 0x7fffu + ((u >> 16) & 1u);          // RNE
    return (unsigned short)(u >> 16);
}
static __device__ __forceinline__ float exp2_fast(float x) {
    float r;
    asm volatile("v_exp_f32 %0, %1" : "=v"(r) : "v"(x));
    return r;
}
static __device__ __forceinline__ unsigned cvt_pk_bf16(float a, float b) {
    unsigned r;                                // low16 = bf16(a), high16 = bf16(b)
    asm("v_cvt_pk_bf16_f32 %0, %1, %2" : "=v"(r) : "v"(a), "v"(b));
    return r;
}
static __device__ __forceinline__ void gload16(const unsigned short* g, unsigned short* lds) {
    __builtin_amdgcn_global_load_lds((const __attribute__((address_space(1))) void*)g,
                                     (__attribute__((address_space(3))) void*)lds, 16, 0, 0);
}

// ---------------- fused prep: hs->bf16 | wqkv permuted concat | wo->bf16 | rope table ----
__global__ __launch_bounds__(256) void k_prep(const float* __restrict__ hs,
                                              const float* __restrict__ wq,
                                              const float* __restrict__ wk,
                                              const float* __restrict__ wv,
                                              const float* __restrict__ wo,
                                              const int* __restrict__ pos_ids,
                                              unsigned short* __restrict__ hsb,
                                              unsigned short* __restrict__ wqkvb,
                                              unsigned short* __restrict__ wob,
                                              float2* __restrict__ tb) {
    long idx = (long)blockIdx.x * 256 + threadIdx.x;
    if (idx < 2097152) {                       // hs -> bf16
        f32x4 v = ((const f32x4*)hs)[idx];
        u16x4 o;
        o.x = f2bf(v.x); o.y = f2bf(v.y); o.z = f2bf(v.z); o.w = f2bf(v.w);
        ((u16x4*)hsb)[idx] = o;
    } else if (idx < 3670016) {                // wqkv concat (q/k col-permuted)
        long i = idx - 2097152;
        long flat = i * 4;
        int row = (int)(flat >> 11);
        int col = (int)(flat & 2047);
        const float* src;
        if (row < 2560) {
            int base = row & 2047;
            int hh = base >> 7, ii = base & 127;
            int d = (ii >> 1) + ((ii & 1) << 6);
            src = (row < 2048 ? wq : wk) + (size_t)(hh * 128 + d) * 2048;
        } else {
            src = wv + (size_t)(row - 2560) * 2048;
        }
        f32x4 v = *(const f32x4*)(src + col);
        u16x4 o;
        o.x = f2bf(v.x); o.y = f2bf(v.y); o.z = f2bf(v.z); o.w = f2bf(v.w);
        *(u16x4*)(wqkvb + flat) = o;
    } else if (idx < 4718592) {                // wo -> bf16
        long i = idx - 3670016;
        f32x4 v = ((const f32x4*)wo)[i];
        u16x4 o;
        o.x = f2bf(v.x); o.y = f2bf(v.y); o.z = f2bf(v.z); o.w = f2bf(v.w);
        ((u16x4*)wob)[i] = o;
    } else {                                   // rope table (f32 fast path)
        long j = idx - 4718592;                // [0, 262144)
        int r = (int)(j >> 6);
        int i = (int)(j & 63);
        float pos = (float)pos_ids[r];
        float invf = exp2f((float)i * -0.20762050593046f);  // 10000^(-i/64)
        float arg  = pos * invf;
        float s, c;
        sincosf(arg, &s, &c);                  // accurate f32 sincos
        tb[(size_t)r * 64 + i] = make_float2(c, s);
    }
}

// ---------------- GEMM (R6 known-good): C[M][N] = A[M][K] * W[N][K]^T ----------------
// 128x128 tile, BK=32, 4 waves (2x2), dbuf LDS + global_load_lds w16 + counted vmcnt.
// XCD-aware bijective block swizzle.
// EPI 0: f32 store (O-proj). EPI 1: fused QKV epilogue (RoPE q/k, V transposed to vt).
template <int EPI>
__global__ __launch_bounds__(256) void k_gemm(const unsigned short* __restrict__ A,
                                              const unsigned short* __restrict__ W,
                                              float* __restrict__ Cf,
                                              unsigned short* __restrict__ qkvt,
                                              unsigned short* __restrict__ vtb,
                                              const float2* __restrict__ tb,
                                              int M, int N, int K) {
    __shared__ unsigned short As[2][4096];   // 128 rows x 32 shorts
    __shared__ unsigned short Ws[2][4096];
    const int tid = threadIdx.x;
    const int lane = tid & 63;
    const int w = tid >> 6;
    const int q = lane & 15, g = lane >> 4;
    const int wr = w >> 1, wc = w & 1;

    // XCD swizzle (bijective: gridDim.x*gridDim.y % 8 == 0)
    const int nwg = gridDim.x * gridDim.y;
    const int id = blockIdx.y * gridDim.x + blockIdx.x;
    const int swz_id = (id & 7) * (nwg >> 3) + (id >> 3);
    const int bx = swz_id % gridDim.x;
    const int by = swz_id / gridDim.x;
    const long mbase = (long)by * 128;
    const long nbase = (long)bx * 128;

    const unsigned short* gA[2];
    const unsigned short* gW[2];
    #pragma unroll
    for (int j = 0; j < 2; ++j) {
        int r = j * 64 + (tid >> 2);
        int slot = (tid & 3) ^ ((r >> 1) & 3);
        gA[j] = A + (size_t)(mbase + r) * K + slot * 8;
        gW[j] = W + (size_t)(nbase + r) * K + slot * 8;
    }
    const int sa = (g ^ ((q >> 1) & 3)) * 8;   // read slot offset (shorts)

    f32x4 acc[4][4];
    #pragma unroll
    for (int m = 0; m < 4; ++m)
        #pragma unroll
        for (int n = 0; n < 4; ++n) acc[m][n] = (f32x4){0.f, 0.f, 0.f, 0.f};

    auto STAGE = [&](int buf) {
        #pragma unroll
        for (int j = 0; j < 2; ++j) {
            gload16(gA[j], &As[buf][j * 2048 + w * 512]);
            gload16(gW[j], &Ws[buf][j * 2048 + w * 512]);
            gA[j] += 32; gW[j] += 32;
        }
    };

    const int nk = K >> 5;
    STAGE(0);
    int cur = 0;
    for (int t = 0; t < nk; ++t) {
        if (t) __builtin_amdgcn_s_barrier();            // prev buffer free
        if (t + 1 < nk) {
            STAGE(cur ^ 1);
            asm volatile("s_waitcnt vmcnt(4)" ::: "memory");   // this tile's loads done
        } else {
            asm volatile("s_waitcnt vmcnt(0)" ::: "memory");
        }
        __builtin_amdgcn_s_barrier();                   // tile visible to all waves

        short8 af[4], bfr[4];
        #pragma unroll
        for (int m = 0; m < 4; ++m) af[m] = *(const short8*)&As[cur][(wr * 64 + m * 16 + q) * 32 + sa];
        #pragma unroll
        for (int n = 0; n < 4; ++n) bfr[n] = *(const short8*)&Ws[cur][(wc * 64 + n * 16 + q) * 32 + sa];
        #pragma unroll
        for (int m = 0; m < 4; ++m)
            #pragma unroll
            for (int n = 0; n < 4; ++n)
                acc[m][n] = __builtin_amdgcn_mfma_f32_16x16x32_bf16(af[m], bfr[n], acc[m][n], 0, 0, 0);
        cur ^= 1;
    }

    if (EPI == 0) {
        #pragma unroll
        for (int m = 0; m < 4; ++m)
            #pragma unroll
            for (int n = 0; n < 4; ++n)
                #pragma unroll
                for (int rr = 0; rr < 4; ++rr) {
                    long row = mbase + wr * 64 + m * 16 + 4 * g + rr;
                    long col = nbase + wc * 64 + n * 16 + q;
                    Cf[row * N + col] = acc[m][n][rr];
                }
    } else {
        const int tile = bx;
        if (tile >= 20) {
            // V tile -> vt[(b*4+kv)*128+c][s], 4 consecutive s per store
            const int kv = tile - 20;
            #pragma unroll
            for (int m = 0; m < 4; ++m)
                #pragma unroll
                for (int n = 0; n < 4; ++n) {
                    int c = wc * 64 + n * 16 + q;
                    long r0 = mbase + wr * 64 + m * 16 + 4 * g;
                    int b = (int)(r0 >> 11), s0 = (int)(r0 & 2047);
                    uint2 pk;
                    pk.x = cvt_pk_bf16(acc[m][n][0], acc[m][n][1]);
                    pk.y = cvt_pk_bf16(acc[m][n][2], acc[m][n][3]);
                    *(uint2*)(vtb + (size_t)((b * 4 + kv) * 128 + c) * 2048 + s0) = pk;
                }
        } else {
            // q/k tile: RoPE from permuted cols; un-permute on store
            const float scale = (tile < 16) ? 0.12751744f : 1.0f;  // (1/sqrt(128))*log2e for q
            const float sgn = (q & 1) ? 1.f : -1.f;
            #pragma unroll
            for (int m = 0; m < 4; ++m)
                #pragma unroll
                for (int rr = 0; rr < 4; ++rr) {
                    long row = mbase + wr * 64 + m * 16 + 4 * g + rr;
                    #pragma unroll
                    for (int n = 0; n < 4; ++n) {
                        int c = wc * 64 + n * 16 + q;
                        float x = acc[m][n][rr];
                        float p = __shfl_xor(x, 1);
                        float2 cs = tb[row * 64 + (c >> 1)];
                        float y = (x * cs.x + sgn * (p * cs.y)) * scale;
                        int dorig = (c >> 1) + ((c & 1) << 6);
                        long col = (tile < 16) ? (tile * 128 + dorig)
                                               : (2048 + (tile - 16) * 128 + dorig);
                        qkvt[row * 3072 + col] = f2bf(y);
                    }
                }
        }
    }
}

// ---------------- Flash attention (R9 measured-best config) ----------------
// 512 blocks (one (b,kvh) per XCD), 4 waves x 32 queries, KVBLK=64, exp2-domain softmax.
// K and V LDS-staged (dbuf, gload_lds, XOR-swizzle), counted vmcnt(8).
// cvt_pk P-packing, rcp normalize, shfl_xor reduces, no setprio.
__global__ __launch_bounds__(256, 2) void k_flash(const unsigned short* __restrict__ qkv,
                                                  const unsigned short* __restrict__ vt,
                                                  unsigned short* __restrict__ aout) {
    __shared__ unsigned short Ks[2][8192];   // 64 keys x 128 hd, dbuf
    __shared__ unsigned short Vs[2][8192];   // 128 d x 64 keys, dbuf
    __shared__ unsigned short Plds[4][1152]; // per-wave 16 x 72
    const int wg = blockIdx.x;
    const int kvg = wg & 7;            // b*4+kvh -> pinned per XCD
    const int inner = wg >> 3;         // 0..63
    const int h_in = inner & 3;
    const int qt = inner >> 2;         // 0..15
    const int b = kvg >> 2, kvh = kvg & 3;
    const int h = kvh * 4 + h_in;
    const int tid = threadIdx.x;
    const int w = tid >> 6, lane = tid & 63;
    const int q = lane & 15, g = lane >> 4;
    const int qrow = qt * 128 + w * 32;

    short8 qf[2][4];
    #pragma unroll
    for (int u = 0; u < 2; ++u) {
        const unsigned short* Qp = qkv + (size_t)(b * 2048 + qrow + u * 16 + q) * 3072 + h * 128 + g * 8;
        #pragma unroll
        for (int t = 0; t < 4; ++t) qf[u][t] = *(const short8*)(Qp + t * 32);
    }

    const unsigned short* Kbase = qkv + (size_t)(b * 2048) * 3072 + 2048 + kvh * 128;
    const unsigned short* Vbase = vt + (size_t)((b * 4 + kvh) * 128) * 2048;
    const unsigned short* gK[4];
    const unsigned short* gV[4];
    #pragma unroll
    for (int i = 0; i < 4; ++i) {
        int rowK = w * 16 + i * 4 + (lane >> 4);
        gK[i] = Kbase + (size_t)rowK * 3072 + (((lane & 15) ^ (rowK & 7)) << 3);
        int rowV = w * 32 + i * 8 + (lane >> 3);
        gV[i] = Vbase + (size_t)rowV * 2048 + (((lane & 7) ^ (rowV & 7)) << 3);
    }

    const int swz = (q & 7) << 3;
    int tcK[4];
    #pragma unroll
    for (int t = 0; t < 4; ++t) tcK[t] = (t * 32 + g * 8) ^ swz;

    unsigned short* Pw = Plds[w];

    float m_run[2] = {-INFINITY, -INFINITY};
    float l_run[2] = {0.f, 0.f};
    f32x4 o[2][8];
    #pragma unroll
    for (int u = 0; u < 2; ++u)
        #pragma unroll
        for (int nf = 0; nf < 8; ++nf) o[u][nf] = (f32x4){0.f, 0.f, 0.f, 0.f};

    auto STAGE = [&](int buf) {
        #pragma unroll
        for (int i = 0; i < 4; ++i) {
            gload16(gK[i], &Ks[buf][w * 2048 + i * 512]);
            gload16(gV[i], &Vs[buf][w * 2048 + i * 512]);
            gK[i] += 64 * 3072;
            gV[i] += 64;
        }
    };

    STAGE(0);
    int cur = 0;
    for (int t0 = 0; t0 < 32; ++t0) {
        if (t0 > 0) __builtin_amdgcn_s_barrier();
        if (t0 + 1 < 32) {
            STAGE(cur ^ 1);
            asm volatile("s_waitcnt vmcnt(8)" ::: "memory");
        } else {
            asm volatile("s_waitcnt vmcnt(0)" ::: "memory");
        }
        __builtin_amdgcn_s_barrier();

        const unsigned short* Kt = Ks[cur];
        const unsigned short* Vt = Vs[cur];

        f32x4 st[2][4];
        #pragma unroll
        for (int ks = 0; ks < 4; ++ks) {
            f32x4 a0 = (f32x4){0.f, 0.f, 0.f, 0.f};
            f32x4 a1 = (f32x4){0.f, 0.f, 0.f, 0.f};
            int rb = (ks * 16 + q) * 128;
            #pragma unroll
            for (int t = 0; t < 4; ++t) {
                short8 kf = *(const short8*)&Kt[rb + tcK[t]];
                a0 = __builtin_amdgcn_mfma_f32_16x16x32_bf16(kf, qf[0][t], a0, 0, 0, 0);
                a1 = __builtin_amdgcn_mfma_f32_16x16x32_bf16(kf, qf[1][t], a1, 0, 0, 0);
            }
            st[0][ks] = a0; st[1][ks] = a1;
        }

        short8 vf[8][2];
        #pragma unroll
        for (int nf = 0; nf < 8; ++nf) {
            int rb = (nf * 16 + q) * 64;
            #pragma unroll
            for (int t = 0; t < 2; ++t) vf[nf][t] = *(const short8*)&Vt[rb + tcK[t]];
        }

        #pragma unroll
        for (int u = 0; u < 2; ++u) {
            float mx = fmaxf(
                fmaxf(fmaxf(fmaxf(st[u][0][0], st[u][0][1]), fmaxf(st[u][0][2], st[u][0][3])),
                      fmaxf(fmaxf(st[u][1][0], st[u][1][1]), fmaxf(st[u][1][2], st[u][1][3]))),
                fmaxf(fmaxf(fmaxf(st[u][2][0], st[u][2][1]), fmaxf(st[u][2][2], st[u][2][3])),
                      fmaxf(fmaxf(st[u][3][0], st[u][3][1]), fmaxf(st[u][3][2], st[u][3][3]))));
            mx = fmaxf(mx, __shfl_xor(mx, 16));
            mx = fmaxf(mx, __shfl_xor(mx, 32));
            if (__any(mx - m_run[u] > 8.0f)) {          // defer-max (exp2 domain)
                float mn = fmaxf(m_run[u], mx);
                float sc = exp2_fast(m_run[u] - mn);
                l_run[u] *= sc;
                f32x4 sv;
                #pragma unroll
                for (int rr = 0; rr < 4; ++rr) sv[rr] = __shfl(sc, 4 * g + rr);
                #pragma unroll
                for (int nf = 0; nf < 8; ++nf) o[u][nf] *= sv;
                m_run[u] = mn;
            }
            f32x4 pe[4];
            #pragma unroll
            for (int ks = 0; ks < 4; ++ks)
                #pragma unroll
                for (int rr = 0; rr < 4; ++rr) pe[ks][rr] = exp2_fast(st[u][ks][rr] - m_run[u]);
            f32x4 ls4 = (pe[0] + pe[1]) + (pe[2] + pe[3]);
            float ls = (ls4[0] + ls4[1]) + (ls4[2] + ls4[3]);
            ls += __shfl_xor(ls, 16);
            ls += __shfl_xor(ls, 32);
            l_run[u] += ls;

            #pragma unroll
            for (int ks = 0; ks < 4; ++ks) {
                uint2 pk;
                pk.x = cvt_pk_bf16(pe[ks][0], pe[ks][1]);
                pk.y = cvt_pk_bf16(pe[ks][2], pe[ks][3]);
                *(uint2*)&Pw[q * 72 + ks * 16 + 4 * g] = pk;
            }
            asm volatile("s_waitcnt lgkmcnt(0)" ::: "memory");
            short8 pa0 = *(const short8*)&Pw[q * 72 + g * 8];
            short8 pa1 = *(const short8*)&Pw[q * 72 + 32 + g * 8];

            #pragma unroll
            for (int nf = 0; nf < 8; ++nf) {
                f32x4 a = o[u][nf];
                a = __builtin_amdgcn_mfma_f32_16x16x32_bf16(pa0, vf[nf][0], a, 0, 0, 0);
                a = __builtin_amdgcn_mfma_f32_16x16x32_bf16(pa1, vf[nf][1], a, 0, 0, 0);
                o[u][nf] = a;
            }
        }
        cur ^= 1;
    }

    #pragma unroll
    for (int u = 0; u < 2; ++u) {
        f32x4 li;
        #pragma unroll
        for (int rr = 0; rr < 4; ++rr) li[rr] = __shfl(l_run[u], 4 * g + rr);
        #pragma unroll
        for (int rr = 0; rr < 4; ++rr) li[rr] = 1.0f / li[rr];
        #pragma unroll
        for (int nf = 0; nf < 8; ++nf)
            #pragma unroll
            for (int rr = 0; rr < 4; ++rr) {
                size_t row = (size_t)(b * 2048 + qrow + u * 16 + 4 * g + rr);
                aout[row * 2048 + h * 128 + nf * 16 + q] = f2bf(o[u][nf][rr] * li[rr]);
            }
    }
}

extern "C" void kernel_launch(void* const* d_in, const int* in_sizes, int n_in,
                              void* d_out, int out_size, void* d_ws, size_t ws_size,
                              hipStream_t stream) {
    (void)in_sizes; (void)n_in; (void)out_size; (void)ws_size;
    const float* hs = (const float*)d_in[0];
    const int* pos  = (const int*)d_in[1];
    const float* wq = (const float*)d_in[2];
    const float* wk = (const float*)d_in[3];
    const float* wv = (const float*)d_in[4];
    const float* wo = (const float*)d_in[5];
    float* out = (float*)d_out;

    unsigned short* hsb   = (unsigned short*)d_ws;              // 4096*2048
    unsigned short* wqkvb = hsb + (size_t)4096 * 2048;          // 3072*2048
    unsigned short* wob   = wqkvb + (size_t)3072 * 2048;        // 2048*2048
    unsigned short* qkvt  = wob + (size_t)2048 * 2048;          // 4096*3072 (q|k used)
    unsigned short* vtb   = qkvt + (size_t)4096 * 3072;         // 8*128*2048
    float2* tb            = (float2*)(vtb + (size_t)8 * 128 * 2048);   // 4096*64
    unsigned short* aoutb = (unsigned short*)(tb + (size_t)4096 * 64); // 4096*2048

    k_prep<<<19456, 256, 0, stream>>>(hs, wq, wk, wv, wo, pos, hsb, wqkvb, wob, tb);
    k_gemm<1><<<dim3(24, 32), 256, 0, stream>>>(hsb, wqkvb, nullptr, qkvt, vtb, tb, 4096, 3072, 2048);
    k_flash<<<dim3(512), 256, 0, stream>>>(qkvt, vtb, aoutb);
    k_gemm<0><<<dim3(16, 32), 256, 0, stream>>>(aoutb, wob, out, nullptr, nullptr, nullptr, 4096, 2048, 2048);
}

// Round 14
// 215.090 us; speedup vs baseline: 1.0397x; 1.0196x over previous
//
#include <hip/hip_runtime.h>
#include <hip/hip_bf16.h>
#include <math.h>

// B=2, S=2048, D=2048, H=16, KV=4, HD=128, n_rep=4
// qkv layout per row (b*2048+s): [0,2048) q | [2048,2560) k  (v goes straight to vt)
// wqkv is column-PERMUTED for q/k heads: head-local col c holds orig d = (c>>1)+((c&1)<<6)
// Q is scaled by (1/sqrt(128))*log2(e): flash softmax runs in exp2 domain.

typedef __attribute__((ext_vector_type(4))) float f32x4;
typedef __attribute__((ext_vector_type(8))) short short8;
typedef __attribute__((ext_vector_type(4))) unsigned short u16x4;
typedef __attribute__((ext_vector_type(8))) unsigned short u16x8;

static __device__ __forceinline__ unsigned short f2bf(float x) {
    unsigned u = __builtin_bit_cast(unsigned, x);
    u += 0x7fffu + ((u >> 16) & 1u);          // RNE
    return (unsigned short)(u >> 16);
}
static __device__ __forceinline__ float exp2_fast(float x) {
    float r;
    asm volatile("v_exp_f32 %0, %1" : "=v"(r) : "v"(x));
    return r;
}
static __device__ __forceinline__ unsigned cvt_pk_bf16(float a, float b) {
    unsigned r;                                // low16 = bf16(a), high16 = bf16(b)
    asm("v_cvt_pk_bf16_f32 %0, %1, %2" : "=v"(r) : "v"(a), "v"(b));
    return r;
}
static __device__ __forceinline__ void gload16(const unsigned short* g, unsigned short* lds) {
    __builtin_amdgcn_global_load_lds((const __attribute__((address_space(1))) void*)g,
                                     (__attribute__((address_space(3))) void*)lds, 16, 0, 0);
}

// ---------------- fused prep: hs->bf16 | wqkv permuted concat | wo->bf16 | rope table ----
__global__ __launch_bounds__(256) void k_prep(const float* __restrict__ hs,
                                              const float* __restrict__ wq,
                                              const float* __restrict__ wk,
                                              const float* __restrict__ wv,
                                              const float* __restrict__ wo,
                                              const int* __restrict__ pos_ids,
                                              unsigned short* __restrict__ hsb,
                                              unsigned short* __restrict__ wqkvb,
                                              unsigned short* __restrict__ wob,
                                              float2* __restrict__ tb) {
    long idx = (long)blockIdx.x * 256 + threadIdx.x;
    if (idx < 2097152) {                       // hs -> bf16
        f32x4 v = ((const f32x4*)hs)[idx];
        u16x4 o;
        o.x = f2bf(v.x); o.y = f2bf(v.y); o.z = f2bf(v.z); o.w = f2bf(v.w);
        ((u16x4*)hsb)[idx] = o;
    } else if (idx < 3670016) {                // wqkv concat (q/k col-permuted)
        long i = idx - 2097152;
        long flat = i * 4;
        int row = (int)(flat >> 11);
        int col = (int)(flat & 2047);
        const float* src;
        if (row < 2560) {
            int base = row & 2047;
            int hh = base >> 7, ii = base & 127;
            int d = (ii >> 1) + ((ii & 1) << 6);
            src = (row < 2048 ? wq : wk) + (size_t)(hh * 128 + d) * 2048;
        } else {
            src = wv + (size_t)(row - 2560) * 2048;
        }
        f32x4 v = *(const f32x4*)(src + col);
        u16x4 o;
        o.x = f2bf(v.x); o.y = f2bf(v.y); o.z = f2bf(v.z); o.w = f2bf(v.w);
        *(u16x4*)(wqkvb + flat) = o;
    } else if (idx < 4718592) {                // wo -> bf16
        long i = idx - 3670016;
        f32x4 v = ((const f32x4*)wo)[i];
        u16x4 o;
        o.x = f2bf(v.x); o.y = f2bf(v.y); o.z = f2bf(v.z); o.w = f2bf(v.w);
        ((u16x4*)wob)[i] = o;
    } else {                                   // rope table (f32 fast path)
        long j = idx - 4718592;                // [0, 262144)
        int r = (int)(j >> 6);
        int i = (int)(j & 63);
        float pos = (float)pos_ids[r];
        float invf = exp2f((float)i * -0.20762050593046f);  // 10000^(-i/64)
        float arg  = pos * invf;
        float s, c;
        sincosf(arg, &s, &c);                  // accurate f32 sincos
        tb[(size_t)r * 64 + i] = make_float2(c, s);
    }
}

// ---------------- GEMM (R6 known-good): C[M][N] = A[M][K] * W[N][K]^T ----------------
// 128x128 tile, BK=32, 4 waves (2x2), dbuf LDS + global_load_lds w16 + counted vmcnt.
// XCD-aware bijective block swizzle.
// EPI 0: f32 store (O-proj). EPI 1: fused QKV epilogue (RoPE q/k, V transposed to vt).
template <int EPI>
__global__ __launch_bounds__(256) void k_gemm(const unsigned short* __restrict__ A,
                                              const unsigned short* __restrict__ W,
                                              float* __restrict__ Cf,
                                              unsigned short* __restrict__ qkvt,
                                              unsigned short* __restrict__ vtb,
                                              const float2* __restrict__ tb,
                                              int M, int N, int K) {
    __shared__ unsigned short As[2][4096];   // 128 rows x 32 shorts
    __shared__ unsigned short Ws[2][4096];
    const int tid = threadIdx.x;
    const int lane = tid & 63;
    const int w = tid >> 6;
    const int q = lane & 15, g = lane >> 4;
    const int wr = w >> 1, wc = w & 1;

    // XCD swizzle (bijective: gridDim.x*gridDim.y % 8 == 0)
    const int nwg = gridDim.x * gridDim.y;
    const int id = blockIdx.y * gridDim.x + blockIdx.x;
    const int swz_id = (id & 7) * (nwg >> 3) + (id >> 3);
    const int bx = swz_id % gridDim.x;
    const int by = swz_id / gridDim.x;
    const long mbase = (long)by * 128;
    const long nbase = (long)bx * 128;

    const unsigned short* gA[2];
    const unsigned short* gW[2];
    #pragma unroll
    for (int j = 0; j < 2; ++j) {
        int r = j * 64 + (tid >> 2);
        int slot = (tid & 3) ^ ((r >> 1) & 3);
        gA[j] = A + (size_t)(mbase + r) * K + slot * 8;
        gW[j] = W + (size_t)(nbase + r) * K + slot * 8;
    }
    const int sa = (g ^ ((q >> 1) & 3)) * 8;   // read slot offset (shorts)

    f32x4 acc[4][4];
    #pragma unroll
    for (int m = 0; m < 4; ++m)
        #pragma unroll
        for (int n = 0; n < 4; ++n) acc[m][n] = (f32x4){0.f, 0.f, 0.f, 0.f};

    auto STAGE = [&](int buf) {
        #pragma unroll
        for (int j = 0; j < 2; ++j) {
            gload16(gA[j], &As[buf][j * 2048 + w * 512]);
            gload16(gW[j], &Ws[buf][j * 2048 + w * 512]);
            gA[j] += 32; gW[j] += 32;
        }
    };

    const int nk = K >> 5;
    STAGE(0);
    int cur = 0;
    for (int t = 0; t < nk; ++t) {
        if (t) __builtin_amdgcn_s_barrier();            // prev buffer free
        if (t + 1 < nk) {
            STAGE(cur ^ 1);
            asm volatile("s_waitcnt vmcnt(4)" ::: "memory");   // this tile's loads done
        } else {
            asm volatile("s_waitcnt vmcnt(0)" ::: "memory");
        }
        __builtin_amdgcn_s_barrier();                   // tile visible to all waves

        short8 af[4], bfr[4];
        #pragma unroll
        for (int m = 0; m < 4; ++m) af[m] = *(const short8*)&As[cur][(wr * 64 + m * 16 + q) * 32 + sa];
        #pragma unroll
        for (int n = 0; n < 4; ++n) bfr[n] = *(const short8*)&Ws[cur][(wc * 64 + n * 16 + q) * 32 + sa];
        #pragma unroll
        for (int m = 0; m < 4; ++m)
            #pragma unroll
            for (int n = 0; n < 4; ++n)
                acc[m][n] = __builtin_amdgcn_mfma_f32_16x16x32_bf16(af[m], bfr[n], acc[m][n], 0, 0, 0);
        cur ^= 1;
    }

    if (EPI == 0) {
        #pragma unroll
        for (int m = 0; m < 4; ++m)
            #pragma unroll
            for (int n = 0; n < 4; ++n)
                #pragma unroll
                for (int rr = 0; rr < 4; ++rr) {
                    long row = mbase + wr * 64 + m * 16 + 4 * g + rr;
                    long col = nbase + wc * 64 + n * 16 + q;
                    Cf[row * N + col] = acc[m][n][rr];
                }
    } else {
        const int tile = bx;
        if (tile >= 20) {
            // V tile -> vt[(b*4+kv)*128+c][s], 4 consecutive s per store
            const int kv = tile - 20;
            #pragma unroll
            for (int m = 0; m < 4; ++m)
                #pragma unroll
                for (int n = 0; n < 4; ++n) {
                    int c = wc * 64 + n * 16 + q;
                    long r0 = mbase + wr * 64 + m * 16 + 4 * g;
                    int b = (int)(r0 >> 11), s0 = (int)(r0 & 2047);
                    uint2 pk;
                    pk.x = cvt_pk_bf16(acc[m][n][0], acc[m][n][1]);
                    pk.y = cvt_pk_bf16(acc[m][n][2], acc[m][n][3]);
                    *(uint2*)(vtb + (size_t)((b * 4 + kv) * 128 + c) * 2048 + s0) = pk;
                }
        } else {
            // q/k tile: RoPE from permuted cols; un-permute on store
            const float scale = (tile < 16) ? 0.12751744f : 1.0f;  // (1/sqrt(128))*log2e for q
            const float sgn = (q & 1) ? 1.f : -1.f;
            #pragma unroll
            for (int m = 0; m < 4; ++m)
                #pragma unroll
                for (int rr = 0; rr < 4; ++rr) {
                    long row = mbase + wr * 64 + m * 16 + 4 * g + rr;
                    #pragma unroll
                    for (int n = 0; n < 4; ++n) {
                        int c = wc * 64 + n * 16 + q;
                        float x = acc[m][n][rr];
                        float p = __shfl_xor(x, 1);
                        float2 cs = tb[row * 64 + (c >> 1)];
                        float y = (x * cs.x + sgn * (p * cs.y)) * scale;
                        int dorig = (c >> 1) + ((c & 1) << 6);
                        long col = (tile < 16) ? (tile * 128 + dorig)
                                               : (2048 + (tile - 16) * 128 + dorig);
                        qkvt[row * 3072 + col] = f2bf(y);
                    }
                }
        }
    }
}

// ---------------- Flash attention v14: KVBLK=128, 8 waves, halved iteration count ----
// 256 blocks (one (b,kvh) per XCD), 8 waves x 32 queries, 16 staged tiles of 128 keys.
// K and V LDS-staged (dbuf, gload_lds, XOR-swizzle), counted vmcnt(8), 143.5KB LDS.
// Softmax once per 128 keys; P bounced as two 64-key sub-tiles (same-wave in-order DS).
__global__ __launch_bounds__(512, 2) void k_flash(const unsigned short* __restrict__ qkv,
                                                  const unsigned short* __restrict__ vt,
                                                  unsigned short* __restrict__ aout) {
    __shared__ unsigned short Ks[2][16384];  // 128 keys x 128 hd, dbuf
    __shared__ unsigned short Vs[2][16384];  // 128 d x 128 keys, dbuf
    __shared__ unsigned short Plds[8][1152]; // per-wave 16 x 72
    const int wg = blockIdx.x;
    const int kvg = wg & 7;            // b*4+kvh -> pinned per XCD
    const int inner = wg >> 3;         // 0..31
    const int h_in = inner & 3;
    const int qt = inner >> 2;         // 0..7
    const int b = kvg >> 2, kvh = kvg & 3;
    const int h = kvh * 4 + h_in;
    const int tid = threadIdx.x;       // 0..511
    const int w = tid >> 6, lane = tid & 63;
    const int q = lane & 15, g = lane >> 4;
    const int qrow = qt * 256 + w * 32;

    short8 qf[2][4];
    #pragma unroll
    for (int u = 0; u < 2; ++u) {
        const unsigned short* Qp = qkv + (size_t)(b * 2048 + qrow + u * 16 + q) * 3072 + h * 128 + g * 8;
        #pragma unroll
        for (int t = 0; t < 4; ++t) qf[u][t] = *(const short8*)(Qp + t * 32);
    }

    const unsigned short* Kbase = qkv + (size_t)(b * 2048) * 3072 + 2048 + kvh * 128;
    const unsigned short* Vbase = vt + (size_t)((b * 4 + kvh) * 128) * 2048;
    const unsigned short* gK[4];
    const unsigned short* gV[4];
    #pragma unroll
    for (int i = 0; i < 4; ++i) {
        int rK = i * 32 + (tid >> 4);                 // 0..127
        int sl = ((tid & 15) ^ (rK & 7)) << 3;        // pre-swizzled slot (shorts)
        gK[i] = Kbase + (size_t)rK * 3072 + sl;
        gV[i] = Vbase + (size_t)rK * 2048 + sl;
    }

    const int q7 = q & 7;
    int tc[4];
    #pragma unroll
    for (int t = 0; t < 4; ++t) tc[t] = (((t * 4 + g) ^ q7) << 3);

    unsigned short* Pw = Plds[w];

    float m_run[2] = {-INFINITY, -INFINITY};
    float l_run[2] = {0.f, 0.f};
    f32x4 o[2][8];
    #pragma unroll
    for (int u = 0; u < 2; ++u)
        #pragma unroll
        for (int nf = 0; nf < 8; ++nf) o[u][nf] = (f32x4){0.f, 0.f, 0.f, 0.f};

    auto STAGE = [&](int buf) {
        #pragma unroll
        for (int i = 0; i < 4; ++i) {
            gload16(gK[i], &Ks[buf][i * 4096 + w * 512]);
            gload16(gV[i], &Vs[buf][i * 4096 + w * 512]);
            gK[i] += 128 * 3072;
            gV[i] += 128;
        }
    };

    STAGE(0);
    int cur = 0;
    for (int t0 = 0; t0 < 16; ++t0) {
        if (t0 > 0) __builtin_amdgcn_s_barrier();
        if (t0 + 1 < 16) {
            STAGE(cur ^ 1);
            asm volatile("s_waitcnt vmcnt(8)" ::: "memory");
        } else {
            asm volatile("s_waitcnt vmcnt(0)" ::: "memory");
        }
        __builtin_amdgcn_s_barrier();

        const unsigned short* Kt = Ks[cur];
        const unsigned short* Vt = Vs[cur];

        // ---- QK^T: st[u][ks] = S^T[key = ks*16+4g+rr][query q], ks=0..7 ----
        f32x4 st[2][8];
        #pragma unroll
        for (int ks = 0; ks < 8; ++ks) {
            f32x4 a0 = (f32x4){0.f, 0.f, 0.f, 0.f};
            f32x4 a1 = (f32x4){0.f, 0.f, 0.f, 0.f};
            int rb = (ks * 16 + q) * 128;
            #pragma unroll
            for (int t = 0; t < 4; ++t) {
                short8 kf = *(const short8*)&Kt[rb + tc[t]];
                a0 = __builtin_amdgcn_mfma_f32_16x16x32_bf16(kf, qf[0][t], a0, 0, 0, 0);
                a1 = __builtin_amdgcn_mfma_f32_16x16x32_bf16(kf, qf[1][t], a1, 0, 0, 0);
            }
            st[0][ks] = a0; st[1][ks] = a1;
        }

        // ---- softmax over 128 keys per group (exp2 domain, defer-max) ----
        #pragma unroll
        for (int u = 0; u < 2; ++u) {
            f32x4 m4 = st[u][0];
            #pragma unroll
            for (int ks = 1; ks < 8; ++ks) {
                #pragma unroll
                for (int rr = 0; rr < 4; ++rr) m4[rr] = fmaxf(m4[rr], st[u][ks][rr]);
            }
            float mx = fmaxf(fmaxf(m4[0], m4[1]), fmaxf(m4[2], m4[3]));
            mx = fmaxf(mx, __shfl_xor(mx, 16));
            mx = fmaxf(mx, __shfl_xor(mx, 32));
            if (__any(mx - m_run[u] > 8.0f)) {
                float mn = fmaxf(m_run[u], mx);
                float sc = exp2_fast(m_run[u] - mn);
                l_run[u] *= sc;
                f32x4 sv;
                #pragma unroll
                for (int rr = 0; rr < 4; ++rr) sv[rr] = __shfl(sc, 4 * g + rr);
                #pragma unroll
                for (int nf = 0; nf < 8; ++nf) o[u][nf] *= sv;
                m_run[u] = mn;
            }
            f32x4 acc4 = (f32x4){0.f, 0.f, 0.f, 0.f};
            #pragma unroll
            for (int ks = 0; ks < 8; ++ks) {
                #pragma unroll
                for (int rr = 0; rr < 4; ++rr) st[u][ks][rr] = exp2_fast(st[u][ks][rr] - m_run[u]);
                acc4 += st[u][ks];
            }
            float ls = (acc4[0] + acc4[1]) + (acc4[2] + acc4[3]);
            ls += __shfl_xor(ls, 16);
            ls += __shfl_xor(ls, 32);
            l_run[u] += ls;
        }

        // ---- two 64-key sub-tiles: P-bounce + PV (same-wave in-order DS) ----
        #pragma unroll
        for (int s = 0; s < 2; ++s) {
            short8 pa[2][2];
            #pragma unroll
            for (int u = 0; u < 2; ++u) {
                #pragma unroll
                for (int kk = 0; kk < 4; ++kk) {
                    f32x4 pv = st[u][s * 4 + kk];
                    uint2 pk;
                    pk.x = cvt_pk_bf16(pv[0], pv[1]);
                    pk.y = cvt_pk_bf16(pv[2], pv[3]);
                    *(uint2*)&Pw[q * 72 + kk * 16 + 4 * g] = pk;
                }
                asm volatile("s_waitcnt lgkmcnt(0)" ::: "memory");
                pa[u][0] = *(const short8*)&Pw[q * 72 + g * 8];
                pa[u][1] = *(const short8*)&Pw[q * 72 + 32 + g * 8];
            }
            #pragma unroll
            for (int nf = 0; nf < 8; ++nf) {
                int rb = (nf * 16 + q) * 128;
                short8 v0 = *(const short8*)&Vt[rb + tc[2 * s]];
                short8 v1 = *(const short8*)&Vt[rb + tc[2 * s + 1]];
                f32x4 a0 = o[0][nf], a1 = o[1][nf];
                a0 = __builtin_amdgcn_mfma_f32_16x16x32_bf16(pa[0][0], v0, a0, 0, 0, 0);
                a0 = __builtin_amdgcn_mfma_f32_16x16x32_bf16(pa[0][1], v1, a0, 0, 0, 0);
                a1 = __builtin_amdgcn_mfma_f32_16x16x32_bf16(pa[1][0], v0, a1, 0, 0, 0);
                a1 = __builtin_amdgcn_mfma_f32_16x16x32_bf16(pa[1][1], v1, a1, 0, 0, 0);
                o[0][nf] = a0; o[1][nf] = a1;
            }
        }
        cur ^= 1;
    }

    #pragma unroll
    for (int u = 0; u < 2; ++u) {
        f32x4 li;
        #pragma unroll
        for (int rr = 0; rr < 4; ++rr) li[rr] = __shfl(l_run[u], 4 * g + rr);
        #pragma unroll
        for (int rr = 0; rr < 4; ++rr) li[rr] = 1.0f / li[rr];
        #pragma unroll
        for (int nf = 0; nf < 8; ++nf)
            #pragma unroll
            for (int rr = 0; rr < 4; ++rr) {
                size_t row = (size_t)(b * 2048 + qrow + u * 16 + 4 * g + rr);
                aout[row * 2048 + h * 128 + nf * 16 + q] = f2bf(o[u][nf][rr] * li[rr]);
            }
    }
}

extern "C" void kernel_launch(void* const* d_in, const int* in_sizes, int n_in,
                              void* d_out, int out_size, void* d_ws, size_t ws_size,
                              hipStream_t stream) {
    (void)in_sizes; (void)n_in; (void)out_size; (void)ws_size;
    const float* hs = (const float*)d_in[0];
    const int* pos  = (const int*)d_in[1];
    const float* wq = (const float*)d_in[2];
    const float* wk = (const float*)d_in[3];
    const float* wv = (const float*)d_in[4];
    const float* wo = (const float*)d_in[5];
    float* out = (float*)d_out;

    unsigned short* hsb   = (unsigned short*)d_ws;              // 4096*2048
    unsigned short* wqkvb = hsb + (size_t)4096 * 2048;          // 3072*2048
    unsigned short* wob   = wqkvb + (size_t)3072 * 2048;        // 2048*2048
    unsigned short* qkvt  = wob + (size_t)2048 * 2048;          // 4096*3072 (q|k used)
    unsigned short* vtb   = qkvt + (size_t)4096 * 3072;         // 8*128*2048
    float2* tb            = (float2*)(vtb + (size_t)8 * 128 * 2048);   // 4096*64
    unsigned short* aoutb = (unsigned short*)(tb + (size_t)4096 * 64); // 4096*2048

    k_prep<<<19456, 256, 0, stream>>>(hs, wq, wk, wv, wo, pos, hsb, wqkvb, wob, tb);
    k_gemm<1><<<dim3(24, 32), 256, 0, stream>>>(hsb, wqkvb, nullptr, qkvt, vtb, tb, 4096, 3072, 2048);
    k_flash<<<dim3(256), 512, 0, stream>>>(qkvt, vtb, aoutb);
    k_gemm<0><<<dim3(16, 32), 256, 0, stream>>>(aoutb, wob, out, nullptr, nullptr, nullptr, 4096, 2048, 2048);
}